// Round 3
// baseline (8001.292 us; speedup 1.0000x reference)
//
#include <hip/hip_runtime.h>

// Bidirectional 2-layer tanh RNN + FC + softmax on MI355X.
// T=512 B=64 I=256 H=512 O=128. fp32 in/out; internally split-bf16 (hi+lo,
// 3 MFMA products) for ~fp32-grade GEMM precision at MFMA rates.
//
// R1 -> R2: ws overflow fix. Flags moved from d_ws into d_out's probs region
// (only written by the final FC GEMM, stream-ordered after both scans), so the
// workspace footprint is EXACTLY 256 MiB: [xwF 64M | xwB 64M | y 128M].
// R2 -> R3: identical resubmit (R2 never ran: GPU acquisition timeout).

#define T_ 512
#define B_ 64
#define I_ 256
#define H_ 512
#define O_ 128

typedef short  bf16x8 __attribute__((ext_vector_type(8)));
typedef float  f32x4  __attribute__((ext_vector_type(4)));

__device__ __forceinline__ unsigned short bf_hi(float x){
  unsigned u = __float_as_uint(x);
  unsigned r = u + 0x7fffu + ((u>>16)&1u);   // RNE to bf16
  return (unsigned short)(r>>16);
}
__device__ __forceinline__ float bf_f(unsigned short h){ return __uint_as_float(((unsigned)h)<<16); }

// float4 -> one 16B LDS quad: [h0 h1 h2 h3 | l0 l1 l2 l3] (bf16 hi/lo split)
__device__ __forceinline__ uint4 pack_quad(float4 v){
  unsigned short h0=bf_hi(v.x), h1=bf_hi(v.y), h2=bf_hi(v.z), h3=bf_hi(v.w);
  unsigned short l0=bf_hi(v.x-bf_f(h0)), l1=bf_hi(v.y-bf_f(h1)),
                 l2=bf_hi(v.z-bf_f(h2)), l3=bf_hi(v.w-bf_f(h3));
  uint4 r;
  r.x = (unsigned)h0 | ((unsigned)h1<<16);
  r.y = (unsigned)h2 | ((unsigned)h3<<16);
  r.z = (unsigned)l0 | ((unsigned)l1<<16);
  r.w = (unsigned)l2 | ((unsigned)l3<<16);
  return r;
}

// two adjacent quads -> (hi8, lo8) fragments; shuffles are register-coalesced (free)
__device__ __forceinline__ void frag_from_quads(const unsigned char* p0, const unsigned char* p1,
                                                bf16x8& hi, bf16x8& lo){
  bf16x8 a = *reinterpret_cast<const bf16x8*>(p0);
  bf16x8 b = *reinterpret_cast<const bf16x8*>(p1);
  hi = __builtin_shufflevector(a,b, 0,1,2,3, 8,9,10,11);
  lo = __builtin_shufflevector(a,b, 4,5,6,7, 12,13,14,15);
}

// ---------------------------------------------------------------------------
// C[M,N] = X[M,K] @ W[N,K]^T + b1 + b2.   128x128 tile, BK=32, 4 waves (2x2),
// reg-staged global->cvt->LDS (fp32 source requires conversion; global_load_lds
// can't convert). 3-term split-bf16 MFMA. Swizzled interleaved-quad LDS rows.
// ---------------------------------------------------------------------------
__global__ __launch_bounds__(256,2)
void gemm_bt(const float* __restrict__ X, const float* __restrict__ W,
             const float* __restrict__ b1, const float* __restrict__ b2,
             float* __restrict__ C, int M, int N, int K)
{
  __shared__ __align__(16) unsigned char lds[32768];   // A:0..16K, B:16K..32K
  const int t = threadIdx.x, lane = t&63, w = t>>6;
  const int wm = w>>1, wn = w&1;
  const int mb = blockIdx.x<<7, nb = blockIdx.y<<7;
  const int nk = K>>5, kf4 = K>>2;
  const float4* Xf4 = reinterpret_cast<const float4*>(X);
  const float4* Wf4 = reinterpret_cast<const float4*>(W);

  f32x4 acc[4][4];
  #pragma unroll
  for(int i=0;i<4;i++)
    #pragma unroll
    for(int j=0;j<4;j++) acc[i][j] = (f32x4){0.f,0.f,0.f,0.f};

  float4 ra[4], rb[4];
  #pragma unroll
  for(int c=0;c<4;c++){
    int idx=(c<<8)+t, row=idx>>3, kq=idx&7;
    ra[c] = Xf4[(size_t)(mb+row)*kf4 + kq];
    rb[c] = Wf4[(size_t)(nb+row)*kf4 + kq];
  }

  for(int kb=0; kb<nk; kb++){
    // write staged regs -> LDS (interleaved hi/lo quads, XOR swizzle)
    #pragma unroll
    for(int c=0;c<4;c++){
      int idx=(c<<8)+t, row=idx>>3, kq=idx&7;
      int swz = (row&7)<<4;
      *reinterpret_cast<uint4*>(lds +         row*128 + ((kq<<4)^swz)) = pack_quad(ra[c]);
      *reinterpret_cast<uint4*>(lds + 16384 + row*128 + ((kq<<4)^swz)) = pack_quad(rb[c]);
    }
    __syncthreads();
    if(kb+1<nk){   // prefetch next tile while MFMAs run
      #pragma unroll
      for(int c=0;c<4;c++){
        int idx=(c<<8)+t, row=idx>>3, kq=idx&7;
        ra[c] = Xf4[(size_t)(mb+row)*kf4 + (size_t)(kb+1)*8 + kq];
        rb[c] = Wf4[(size_t)(nb+row)*kf4 + (size_t)(kb+1)*8 + kq];
      }
    }
    bf16x8 ah[4],al[4],bh[4],bl[4];
    const int q0 = (lane>>4)<<1;     // quad pair base: k = (lane>>4)*8
    #pragma unroll
    for(int i=0;i<4;i++){
      int rowA = (wm<<6) + (i<<4) + (lane&15); int sa=(rowA&7)<<4;
      frag_from_quads(lds + rowA*128 + ((q0<<4)^sa),
                      lds + rowA*128 + (((q0+1)<<4)^sa), ah[i], al[i]);
      int rowB = (wn<<6) + (i<<4) + (lane&15); int sb=(rowB&7)<<4;
      frag_from_quads(lds + 16384 + rowB*128 + ((q0<<4)^sb),
                      lds + 16384 + rowB*128 + (((q0+1)<<4)^sb), bh[i], bl[i]);
    }
    #pragma unroll
    for(int i=0;i<4;i++)
      #pragma unroll
      for(int j=0;j<4;j++){
        acc[i][j] = __builtin_amdgcn_mfma_f32_16x16x32_bf16(ah[i], bh[j], acc[i][j], 0,0,0);
        acc[i][j] = __builtin_amdgcn_mfma_f32_16x16x32_bf16(ah[i], bl[j], acc[i][j], 0,0,0);
        acc[i][j] = __builtin_amdgcn_mfma_f32_16x16x32_bf16(al[i], bh[j], acc[i][j], 0,0,0);
      }
    __syncthreads();
  }

  // epilogue: bias + store (C/D layout: col=lane&15, row=(lane>>4)*4+reg  [m89])
  #pragma unroll
  for(int j=0;j<4;j++){
    int col = nb + (wn<<6) + (j<<4) + (lane&15);
    float bs = (b1?b1[col]:0.f) + (b2?b2[col]:0.f);
    #pragma unroll
    for(int i=0;i<4;i++){
      int r0 = mb + (wm<<6) + (i<<4) + ((lane>>4)<<2);
      #pragma unroll
      for(int r=0;r<4;r++)
        C[(size_t)(r0+r)*N + col] = acc[i][j][r] + bs;
    }
  }
}

// ---------------------------------------------------------------------------
// Persistent bidirectional scan for one layer. 64 blocks =
// 2 dir x 4 batch-groups(16 rows) x 8 j-slices(64 cols). Whh j-slice lives in
// LDS (split-bf16, 128KB). Per step: stage h(t-1) from y (agent-scope atomic
// loads -> fresh past non-coherent XCD L2s), 3-chain split MFMA, tanh, write
// h(t) into y with agent-scope stores, then release a monotonic group counter.
// ---------------------------------------------------------------------------
__global__ __launch_bounds__(256,1)
void rnn_scan(const float* __restrict__ xw_f, const float* __restrict__ xw_b,
              const float* __restrict__ Whh_f, const float* __restrict__ Whh_b,
              const float* __restrict__ h0base,
              float* __restrict__ y,            // [T][B][2H], dir half-written
              float* __restrict__ hT,           // layer base; + dir*B*H inside
              unsigned int* __restrict__ flags) // 8 monotonic counters
{
  __shared__ __align__(16) unsigned char lds[147456];  // Whh 128K + h-chunk 16K
  const int t = threadIdx.x, lane = t&63, w = t>>6;
  const int bid = blockIdx.x;
  const int dir = bid>>5, mg = (bid>>3)&3, js = bid&7;
  const float* xw  = dir ? xw_b : xw_f;
  const float* Whh = dir ? Whh_b : Whh_f;
  const float* h0  = h0base + (size_t)dir*B_*H_;
  unsigned int* flag = flags + dir*4 + mg;

  // one-time Whh slice preload: rows j in [js*64, js*64+64), all K=512
  {
    const float4* Wf4 = reinterpret_cast<const float4*>(Whh);
    #pragma unroll
    for(int c=0;c<32;c++){
      int idx=(c<<8)+t, row=idx>>7, q=idx&127;
      float4 v = Wf4[(size_t)((js<<6)+row)*(H_>>2) + q];
      int swz=(row&7)<<4;
      *reinterpret_cast<uint4*>(lds + (row<<11) + ((q<<4)^swz)) = pack_quad(v);
    }
  }
  __syncthreads();

  const int jg   = (js<<6) + (w<<4) + (lane&15);  // this lane's output column
  const int ml0  = (lane>>4)<<2;                  // C/D local row base
  const int mg16 = mg<<4;

  for(int step=0; step<T_; step++){
    const int tt  = dir ? (T_-1-step) : step;
    const int ttp = dir ? (tt+1) : (tt-1);        // time index of h(t-1) in y

    // prefetch xw[tt] (independent of h) before the spin
    float xv[4];
    #pragma unroll
    for(int r=0;r<4;r++)
      xv[r] = xw[((size_t)tt*B_ + mg16 + ml0 + r)*H_ + jg];

    if(step>0 && t==0){
      unsigned target = 8u*(unsigned)step;
      int guard = 0;  // bounded spin: converts a deadlock into a visible mismatch
      while(__hip_atomic_load(flag, __ATOMIC_RELAXED, __HIP_MEMORY_SCOPE_AGENT) < target
            && ++guard < 1000000) {}
    }
    __syncthreads();
    asm volatile("" ::: "memory");

    f32x4 a0={0.f,0.f,0.f,0.f}, a1=a0, a2=a0;   // 3 independent MFMA chains

    #pragma unroll
    for(int ch=0; ch<2; ch++){
      // stage h chunk: 16 rows x 256 k into LDS @131072
      if(step==0){
        #pragma unroll
        for(int c=0;c<4;c++){
          int idx=(c<<8)+t, row=idx>>6, q=idx&63;
          float4 v = reinterpret_cast<const float4*>(h0)[(size_t)(mg16+row)*(H_>>2) + (ch<<6) + q];
          int swz=(row&7)<<4;
          *reinterpret_cast<uint4*>(lds + 131072 + (row<<10) + ((q<<4)^swz)) = pack_quad(v);
        }
      } else {
        #pragma unroll
        for(int c=0;c<4;c++){
          int idx=(c<<8)+t, row=idx>>6, q=idx&63;
          float* src = y + ((size_t)ttp*B_ + mg16+row)*(2*H_) + dir*H_ + (ch<<8) + (q<<2);
          float4 v;
          v.x = __hip_atomic_load(src+0, __ATOMIC_RELAXED, __HIP_MEMORY_SCOPE_AGENT);
          v.y = __hip_atomic_load(src+1, __ATOMIC_RELAXED, __HIP_MEMORY_SCOPE_AGENT);
          v.z = __hip_atomic_load(src+2, __ATOMIC_RELAXED, __HIP_MEMORY_SCOPE_AGENT);
          v.w = __hip_atomic_load(src+3, __ATOMIC_RELAXED, __HIP_MEMORY_SCOPE_AGENT);
          int swz=(row&7)<<4;
          *reinterpret_cast<uint4*>(lds + 131072 + (row<<10) + ((q<<4)^swz)) = pack_quad(v);
        }
      }
      __syncthreads();

      #pragma unroll
      for(int kk=0; kk<8; kk++){
        int rowA = lane&15, sa=(rowA&7)<<4;
        int qa = (kk<<3) + ((lane>>4)<<1);
        bf16x8 ah, alo;
        frag_from_quads(lds + 131072 + (rowA<<10) + ((qa<<4)^sa),
                        lds + 131072 + (rowA<<10) + (((qa+1)<<4)^sa), ah, alo);
        int rowB = (w<<4) + (lane&15), sb=(rowB&7)<<4;
        int qb = (ch<<6) + (kk<<3) + ((lane>>4)<<1);
        bf16x8 bh, bl;
        frag_from_quads(lds + (rowB<<11) + ((qb<<4)^sb),
                        lds + (rowB<<11) + (((qb+1)<<4)^sb), bh, bl);
        a0 = __builtin_amdgcn_mfma_f32_16x16x32_bf16(ah,  bh, a0, 0,0,0);
        a1 = __builtin_amdgcn_mfma_f32_16x16x32_bf16(ah,  bl, a1, 0,0,0);
        a2 = __builtin_amdgcn_mfma_f32_16x16x32_bf16(alo, bh, a2, 0,0,0);
      }
      __syncthreads();   // before overwriting the h-chunk buffer
    }

    // h = tanh(recur + xw); tanh via exp, clamped (avoids inf/inf NaN)
    float hv[4];
    #pragma unroll
    for(int r=0;r<4;r++){
      float z = a0[r]+a1[r]+a2[r] + xv[r];
      z = fminf(fmaxf(z,-15.f),15.f);
      float e = __expf(2.f*z);
      hv[r] = (e-1.f)/(e+1.f);
    }
    #pragma unroll
    for(int r=0;r<4;r++){
      __hip_atomic_store(y + ((size_t)tt*B_ + mg16+ml0+r)*(2*H_) + dir*H_ + jg, hv[r],
                         __ATOMIC_RELAXED, __HIP_MEMORY_SCOPE_AGENT);
    }
    if(step==T_-1){
      #pragma unroll
      for(int r=0;r<4;r++)
        hT[(size_t)dir*B_*H_ + (size_t)(mg16+ml0+r)*H_ + jg] = hv[r];
    }
    // every thread drains its own stores, then one thread releases the counter
    asm volatile("s_waitcnt vmcnt(0)" ::: "memory");
    __syncthreads();
    if(t==0) __hip_atomic_fetch_add(flag, 1u, __ATOMIC_RELAXED, __HIP_MEMORY_SCOPE_AGENT);
  }
}

// ---------------------------------------------------------------------------
// in-place row softmax over O=128 (one wave per row, 2 elems/lane)
// ---------------------------------------------------------------------------
__global__ __launch_bounds__(256)
void softmax_rows(float* __restrict__ P){
  const int row = (blockIdx.x<<2) + (threadIdx.x>>6);
  const int l = threadIdx.x & 63;
  float2* p = reinterpret_cast<float2*>(P) + (size_t)row*(O_/2) + l;
  float2 v = *p;
  float m = fmaxf(v.x, v.y);
  #pragma unroll
  for(int off=32; off; off>>=1) m = fmaxf(m, __shfl_xor(m, off, 64));
  float e0 = __expf(v.x-m), e1 = __expf(v.y-m);
  float s = e0+e1;
  #pragma unroll
  for(int off=32; off; off>>=1) s += __shfl_xor(s, off, 64);
  float inv = 1.f/s;
  *p = make_float2(e0*inv, e1*inv);
}

// ---------------------------------------------------------------------------
extern "C" void kernel_launch(void* const* d_in, const int* in_sizes, int n_in,
                              void* d_out, int out_size, void* d_ws, size_t ws_size,
                              hipStream_t stream)
{
  (void)in_sizes; (void)n_in; (void)out_size; (void)ws_size;
  const float* x     = (const float*)d_in[0];
  const float* h0    = (const float*)d_in[1];
  const float* Wih0f = (const float*)d_in[2];
  const float* Whh0f = (const float*)d_in[3];
  const float* bih0f = (const float*)d_in[4];
  const float* bhh0f = (const float*)d_in[5];
  const float* Wih0b = (const float*)d_in[6];
  const float* Whh0b = (const float*)d_in[7];
  const float* bih0b = (const float*)d_in[8];
  const float* bhh0b = (const float*)d_in[9];
  const float* Wih1f = (const float*)d_in[10];
  const float* Whh1f = (const float*)d_in[11];
  const float* bih1f = (const float*)d_in[12];
  const float* bhh1f = (const float*)d_in[13];
  const float* Wih1b = (const float*)d_in[14];
  const float* Whh1b = (const float*)d_in[15];
  const float* bih1b = (const float*)d_in[16];
  const float* bhh1b = (const float*)d_in[17];
  const float* Wfc   = (const float*)d_in[18];
  const float* bfc   = (const float*)d_in[19];

  const size_t MR = (size_t)T_*B_;                 // 32768 GEMM rows
  // ws layout (EXACTLY 256 MiB): [xwF 64M | xwB 64M | y 128M]
  float* xwF  = (float*)d_ws;
  float* xwB  = xwF + MR*H_;
  float* bufA = xwF + 2*MR*H_;                     // y0, then y1 in place
  float* probs = (float*)d_out;                    // logits in place, then softmax
  float* hTout = probs + MR*O_;
  // flags live in the probs region of d_out: nothing reads it before the final
  // FC GEMM overwrites it (stream-ordered after both scans). 16 counters used.
  unsigned int* flags = (unsigned int*)d_out;

  hipMemsetAsync(flags, 0, 256, stream);

  dim3 blk(256);
  // layer 0 input projections (K=256)
  gemm_bt<<<dim3(MR/128, H_/128), blk, 0, stream>>>(x, Wih0f, bih0f, bhh0f, xwF, (int)MR, H_, I_);
  gemm_bt<<<dim3(MR/128, H_/128), blk, 0, stream>>>(x, Wih0b, bih0b, bhh0b, xwB, (int)MR, H_, I_);
  // layer 0 scan (both directions) -> y0
  rnn_scan<<<64, blk, 0, stream>>>(xwF, xwB, Whh0f, Whh0b, h0, bufA, hTout, flags);
  // layer 1 input projections (K=1024)
  gemm_bt<<<dim3(MR/128, H_/128), blk, 0, stream>>>(bufA, Wih1f, bih1f, bhh1f, xwF, (int)MR, H_, 2*H_);
  gemm_bt<<<dim3(MR/128, H_/128), blk, 0, stream>>>(bufA, Wih1b, bih1b, bhh1b, xwB, (int)MR, H_, 2*H_);
  // layer 1 scan -> y1 (in place over y0)
  rnn_scan<<<64, blk, 0, stream>>>(xwF, xwB, Whh1f, Whh1b, h0 + 2*B_*H_, bufA, hTout + 2*B_*H_, flags + 8);
  // FC head (K=1024, N=128) -> logits into d_out
  gemm_bt<<<dim3(MR/128, 1), blk, 0, stream>>>(bufA, Wfc, bfc, nullptr, probs, (int)MR, O_, 2*H_);
  // softmax in place
  softmax_rows<<<MR/4, blk, 0, stream>>>(probs);
}

// Round 8
// 4139.619 us; speedup vs baseline: 1.9329x; 1.9329x over previous
//
#include <hip/hip_runtime.h>

// Bidirectional 2-layer tanh RNN + FC + softmax on MI355X.
// T=512 B=64 I=256 H=512 O=128. fp32 in/out; internally split-bf16 (hi+lo,
// 3 MFMA products) for ~fp32-grade GEMM precision at MFMA rates.
//
// R3 -> R4 (scan was 96% of runtime at 7.47us/step, sync-bound: MfmaUtil 1%,
// VALUBusy 3.5%, HBM 2.4%):
//  - flags padded to 256B/flag (R3 had all 16 counters in ONE cacheline:
//    64 RMWs/step + 64 max-rate pollers serialized on it)
//  - s_sleep(1) backoff in the spin loop
//  - h-exchange loads as 64-bit relaxed agent atomics
// R5 -> R6: + single-stage h-exchange: all 16 exchange loads issue at once
//   into one 32KB LDS buffer (was 2 serialized 16KB chunk stages -> paid the
//   cross-XCD LLC RT twice per step). Barriers/step 5 -> 3. LDS = 160 KiB
//   exactly. Sync protocol unchanged from R4.
// R7 -> R8: identical resubmit (R4..R7 never ran: acquisition timeouts).

#define T_ 512
#define B_ 64
#define I_ 256
#define H_ 512
#define O_ 128

typedef short  bf16x8 __attribute__((ext_vector_type(8)));
typedef float  f32x4  __attribute__((ext_vector_type(4)));

__device__ __forceinline__ unsigned short bf_hi(float x){
  unsigned u = __float_as_uint(x);
  unsigned r = u + 0x7fffu + ((u>>16)&1u);   // RNE to bf16
  return (unsigned short)(r>>16);
}
__device__ __forceinline__ float bf_f(unsigned short h){ return __uint_as_float(((unsigned)h)<<16); }

// float4 -> one 16B LDS quad: [h0 h1 h2 h3 | l0 l1 l2 l3] (bf16 hi/lo split)
__device__ __forceinline__ uint4 pack_quad(float4 v){
  unsigned short h0=bf_hi(v.x), h1=bf_hi(v.y), h2=bf_hi(v.z), h3=bf_hi(v.w);
  unsigned short l0=bf_hi(v.x-bf_f(h0)), l1=bf_hi(v.y-bf_f(h1)),
                 l2=bf_hi(v.z-bf_f(h2)), l3=bf_hi(v.w-bf_f(h3));
  uint4 r;
  r.x = (unsigned)h0 | ((unsigned)h1<<16);
  r.y = (unsigned)h2 | ((unsigned)h3<<16);
  r.z = (unsigned)l0 | ((unsigned)l1<<16);
  r.w = (unsigned)l2 | ((unsigned)l3<<16);
  return r;
}

// two adjacent quads -> (hi8, lo8) fragments; shuffles are register-coalesced (free)
__device__ __forceinline__ void frag_from_quads(const unsigned char* p0, const unsigned char* p1,
                                                bf16x8& hi, bf16x8& lo){
  bf16x8 a = *reinterpret_cast<const bf16x8*>(p0);
  bf16x8 b = *reinterpret_cast<const bf16x8*>(p1);
  hi = __builtin_shufflevector(a,b, 0,1,2,3, 8,9,10,11);
  lo = __builtin_shufflevector(a,b, 4,5,6,7, 12,13,14,15);
}

// ---------------------------------------------------------------------------
// C[M,N] = X[M,K] @ W[N,K]^T + b1 + b2.   128x128 tile, BK=32, 4 waves (2x2),
// reg-staged global->cvt->LDS. 3-term split-bf16 MFMA. Swizzled quad rows.
// ---------------------------------------------------------------------------
__global__ __launch_bounds__(256,2)
void gemm_bt(const float* __restrict__ X, const float* __restrict__ W,
             const float* __restrict__ b1, const float* __restrict__ b2,
             float* __restrict__ C, int M, int N, int K)
{
  __shared__ __align__(16) unsigned char lds[32768];   // A:0..16K, B:16K..32K
  const int t = threadIdx.x, lane = t&63, w = t>>6;
  const int wm = w>>1, wn = w&1;
  const int mb = blockIdx.x<<7, nb = blockIdx.y<<7;
  const int nk = K>>5, kf4 = K>>2;
  const float4* Xf4 = reinterpret_cast<const float4*>(X);
  const float4* Wf4 = reinterpret_cast<const float4*>(W);

  f32x4 acc[4][4];
  #pragma unroll
  for(int i=0;i<4;i++)
    #pragma unroll
    for(int j=0;j<4;j++) acc[i][j] = (f32x4){0.f,0.f,0.f,0.f};

  float4 ra[4], rb[4];
  #pragma unroll
  for(int c=0;c<4;c++){
    int idx=(c<<8)+t, row=idx>>3, kq=idx&7;
    ra[c] = Xf4[(size_t)(mb+row)*kf4 + kq];
    rb[c] = Wf4[(size_t)(nb+row)*kf4 + kq];
  }

  for(int kb=0; kb<nk; kb++){
    #pragma unroll
    for(int c=0;c<4;c++){
      int idx=(c<<8)+t, row=idx>>3, kq=idx&7;
      int swz = (row&7)<<4;
      *reinterpret_cast<uint4*>(lds +         row*128 + ((kq<<4)^swz)) = pack_quad(ra[c]);
      *reinterpret_cast<uint4*>(lds + 16384 + row*128 + ((kq<<4)^swz)) = pack_quad(rb[c]);
    }
    __syncthreads();
    if(kb+1<nk){   // prefetch next tile while MFMAs run
      #pragma unroll
      for(int c=0;c<4;c++){
        int idx=(c<<8)+t, row=idx>>3, kq=idx&7;
        ra[c] = Xf4[(size_t)(mb+row)*kf4 + (size_t)(kb+1)*8 + kq];
        rb[c] = Wf4[(size_t)(nb+row)*kf4 + (size_t)(kb+1)*8 + kq];
      }
    }
    bf16x8 ah[4],al[4],bh[4],bl[4];
    const int q0 = (lane>>4)<<1;     // quad pair base: k = (lane>>4)*8
    #pragma unroll
    for(int i=0;i<4;i++){
      int rowA = (wm<<6) + (i<<4) + (lane&15); int sa=(rowA&7)<<4;
      frag_from_quads(lds + rowA*128 + ((q0<<4)^sa),
                      lds + rowA*128 + (((q0+1)<<4)^sa), ah[i], al[i]);
      int rowB = (wn<<6) + (i<<4) + (lane&15); int sb=(rowB&7)<<4;
      frag_from_quads(lds + 16384 + rowB*128 + ((q0<<4)^sb),
                      lds + 16384 + rowB*128 + (((q0+1)<<4)^sb), bh[i], bl[i]);
    }
    #pragma unroll
    for(int i=0;i<4;i++)
      #pragma unroll
      for(int j=0;j<4;j++){
        acc[i][j] = __builtin_amdgcn_mfma_f32_16x16x32_bf16(ah[i], bh[j], acc[i][j], 0,0,0);
        acc[i][j] = __builtin_amdgcn_mfma_f32_16x16x32_bf16(ah[i], bl[j], acc[i][j], 0,0,0);
        acc[i][j] = __builtin_amdgcn_mfma_f32_16x16x32_bf16(al[i], bh[j], acc[i][j], 0,0,0);
      }
    __syncthreads();
  }

  // epilogue: bias + store (C/D layout: col=lane&15, row=(lane>>4)*4+reg  [m89])
  #pragma unroll
  for(int j=0;j<4;j++){
    int col = nb + (wn<<6) + (j<<4) + (lane&15);
    float bs = (b1?b1[col]:0.f) + (b2?b2[col]:0.f);
    #pragma unroll
    for(int i=0;i<4;i++){
      int r0 = mb + (wm<<6) + (i<<4) + ((lane>>4)<<2);
      #pragma unroll
      for(int r=0;r<4;r++)
        C[(size_t)(r0+r)*N + col] = acc[i][j][r] + bs;
    }
  }
}

// ---------------------------------------------------------------------------
// Persistent bidirectional scan for one layer. 64 blocks =
// 2 dir x 4 batch-groups(16 rows) x 8 j-slices(64 cols). Whh j-slice in LDS
// (split-bf16, 128KB) + 32KB h-block buffer (16 rows x 512 k). Per step:
// spin on padded group counter, stage FULL h(t-1) block via 16 pipelined
// 64-bit agent atomics (one LLC RT), 16x3 split MFMA, tanh, agent stores,
// drain, release padded counter.
// ---------------------------------------------------------------------------
__global__ __launch_bounds__(256,1)
void rnn_scan(const float* __restrict__ xw_f, const float* __restrict__ xw_b,
              const float* __restrict__ Whh_f, const float* __restrict__ Whh_b,
              const float* __restrict__ h0base,
              float* __restrict__ y,            // [T][B][2H], dir half-written
              float* __restrict__ hT,           // layer base; + dir*B*H inside
              unsigned int* __restrict__ flags) // padded counters, 64 uints apart
{
  __shared__ __align__(16) unsigned char lds[163840];  // Whh 128K + h-block 32K
  const int t = threadIdx.x, lane = t&63, w = t>>6;
  const int bid = blockIdx.x;
  const int dir = bid>>5, mg = (bid>>3)&3, js = bid&7;
  const float* xw  = dir ? xw_b : xw_f;
  const float* Whh = dir ? Whh_b : Whh_f;
  const float* h0  = h0base + (size_t)dir*B_*H_;
  unsigned int* flag = flags + (dir*4 + mg)*64;   // 256B per counter

  // one-time Whh slice preload: rows j in [js*64, js*64+64), all K=512
  {
    const float4* Wf4 = reinterpret_cast<const float4*>(Whh);
    #pragma unroll
    for(int c=0;c<32;c++){
      int idx=(c<<8)+t, row=idx>>7, q=idx&127;
      float4 v = Wf4[(size_t)((js<<6)+row)*(H_>>2) + q];
      int swz=(row&7)<<4;
      *reinterpret_cast<uint4*>(lds + (row<<11) + ((q<<4)^swz)) = pack_quad(v);
    }
  }
  __syncthreads();

  const int jg   = (js<<6) + (w<<4) + (lane&15);  // this lane's output column
  const int ml0  = (lane>>4)<<2;                  // C/D local row base
  const int mg16 = mg<<4;

  for(int step=0; step<T_; step++){
    const int tt  = dir ? (T_-1-step) : step;
    const int ttp = dir ? (tt+1) : (tt-1);        // time index of h(t-1) in y

    // prefetch xw[tt] (independent of h) before the spin
    float xv[4];
    #pragma unroll
    for(int r=0;r<4;r++)
      xv[r] = xw[((size_t)tt*B_ + mg16 + ml0 + r)*H_ + jg];

    if(step>0 && t==0){
      unsigned target = 8u*(unsigned)step;
      int guard = 0;  // bounded spin: converts a deadlock into a visible mismatch
      while(__hip_atomic_load(flag, __ATOMIC_RELAXED, __HIP_MEMORY_SCOPE_AGENT) < target
            && ++guard < 400000)
        __builtin_amdgcn_s_sleep(1);
    }
    __syncthreads();   // holds all waves until spin done; also fences prior
                       // step's LDS reads (lgkmcnt drained at barrier)
    asm volatile("" ::: "memory");

    // stage FULL h block: 16 rows x 512 k into LDS @131072 (2048 B/row)
    if(step==0){
      #pragma unroll
      for(int c=0;c<8;c++){
        int idx=(c<<8)+t, row=idx>>7, q=idx&127;
        float4 v = reinterpret_cast<const float4*>(h0)[(size_t)(mg16+row)*(H_>>2) + q];
        int swz=(row&7)<<4;
        *reinterpret_cast<uint4*>(lds + 131072 + (row<<11) + ((q<<4)^swz)) = pack_quad(v);
      }
    } else {
      // issue all 16 64-bit agent loads, then pack (loads pipeline: one LLC RT)
      unsigned long long u[16];
      #pragma unroll
      for(int c=0;c<8;c++){
        int idx=(c<<8)+t, row=idx>>7, q=idx&127;
        const unsigned long long* srcq = reinterpret_cast<const unsigned long long*>(
            y + ((size_t)ttp*B_ + mg16+row)*(2*H_) + dir*H_) + (q<<1);
        u[2*c  ] = __hip_atomic_load(srcq,   __ATOMIC_RELAXED, __HIP_MEMORY_SCOPE_AGENT);
        u[2*c+1] = __hip_atomic_load(srcq+1, __ATOMIC_RELAXED, __HIP_MEMORY_SCOPE_AGENT);
      }
      #pragma unroll
      for(int c=0;c<8;c++){
        int idx=(c<<8)+t, row=idx>>7, q=idx&127;
        float4 v;
        v.x = __uint_as_float((unsigned)(u[2*c  ] & 0xffffffffu));
        v.y = __uint_as_float((unsigned)(u[2*c  ] >> 32));
        v.z = __uint_as_float((unsigned)(u[2*c+1] & 0xffffffffu));
        v.w = __uint_as_float((unsigned)(u[2*c+1] >> 32));
        int swz=(row&7)<<4;
        *reinterpret_cast<uint4*>(lds + 131072 + (row<<11) + ((q<<4)^swz)) = pack_quad(v);
      }
    }
    __syncthreads();

    f32x4 a0={0.f,0.f,0.f,0.f}, a1=a0, a2=a0;   // 3 independent MFMA chains
    #pragma unroll
    for(int kk=0; kk<16; kk++){
      int rowA = lane&15, sa=(rowA&7)<<4;
      int qa = (kk<<3) + ((lane>>4)<<1);
      bf16x8 ah, alo;
      frag_from_quads(lds + 131072 + (rowA<<11) + ((qa<<4)^sa),
                      lds + 131072 + (rowA<<11) + (((qa+1)<<4)^sa), ah, alo);
      int rowB = (w<<4) + (lane&15), sb=(rowB&7)<<4;
      int qb = (kk<<3) + ((lane>>4)<<1);
      bf16x8 bh, bl;
      frag_from_quads(lds + (rowB<<11) + ((qb<<4)^sb),
                      lds + (rowB<<11) + (((qb+1)<<4)^sb), bh, bl);
      a0 = __builtin_amdgcn_mfma_f32_16x16x32_bf16(ah,  bh, a0, 0,0,0);
      a1 = __builtin_amdgcn_mfma_f32_16x16x32_bf16(ah,  bl, a1, 0,0,0);
      a2 = __builtin_amdgcn_mfma_f32_16x16x32_bf16(alo, bh, a2, 0,0,0);
    }

    // h = tanh(recur + xw); tanh via exp, clamped (avoids inf/inf NaN)
    float hv[4];
    #pragma unroll
    for(int r=0;r<4;r++){
      float z = a0[r]+a1[r]+a2[r] + xv[r];
      z = fminf(fmaxf(z,-15.f),15.f);
      float e = __expf(2.f*z);
      hv[r] = (e-1.f)/(e+1.f);
    }
    #pragma unroll
    for(int r=0;r<4;r++){
      __hip_atomic_store(y + ((size_t)tt*B_ + mg16+ml0+r)*(2*H_) + dir*H_ + jg, hv[r],
                         __ATOMIC_RELAXED, __HIP_MEMORY_SCOPE_AGENT);
    }
    if(step==T_-1){
      #pragma unroll
      for(int r=0;r<4;r++)
        hT[(size_t)dir*B_*H_ + (size_t)(mg16+ml0+r)*H_ + jg] = hv[r];
    }
    // every thread drains its own stores, then one thread releases the counter
    asm volatile("s_waitcnt vmcnt(0)" ::: "memory");
    __syncthreads();
    if(t==0) __hip_atomic_fetch_add(flag, 1u, __ATOMIC_RELAXED, __HIP_MEMORY_SCOPE_AGENT);
  }
}

// ---------------------------------------------------------------------------
// in-place row softmax over O=128 (one wave per row, 2 elems/lane)
// ---------------------------------------------------------------------------
__global__ __launch_bounds__(256)
void softmax_rows(float* __restrict__ P){
  const int row = (blockIdx.x<<2) + (threadIdx.x>>6);
  const int l = threadIdx.x & 63;
  float2* p = reinterpret_cast<float2*>(P) + (size_t)row*(O_/2) + l;
  float2 v = *p;
  float m = fmaxf(v.x, v.y);
  #pragma unroll
  for(int off=32; off; off>>=1) m = fmaxf(m, __shfl_xor(m, off, 64));
  float e0 = __expf(v.x-m), e1 = __expf(v.y-m);
  float s = e0+e1;
  #pragma unroll
  for(int off=32; off; off>>=1) s += __shfl_xor(s, off, 64);
  float inv = 1.f/s;
  *p = make_float2(e0*inv, e1*inv);
}

// ---------------------------------------------------------------------------
extern "C" void kernel_launch(void* const* d_in, const int* in_sizes, int n_in,
                              void* d_out, int out_size, void* d_ws, size_t ws_size,
                              hipStream_t stream)
{
  (void)in_sizes; (void)n_in; (void)out_size; (void)ws_size;
  const float* x     = (const float*)d_in[0];
  const float* h0    = (const float*)d_in[1];
  const float* Wih0f = (const float*)d_in[2];
  const float* Whh0f = (const float*)d_in[3];
  const float* bih0f = (const float*)d_in[4];
  const float* bhh0f = (const float*)d_in[5];
  const float* Wih0b = (const float*)d_in[6];
  const float* Whh0b = (const float*)d_in[7];
  const float* bih0b = (const float*)d_in[8];
  const float* bhh0b = (const float*)d_in[9];
  const float* Wih1f = (const float*)d_in[10];
  const float* Whh1f = (const float*)d_in[11];
  const float* bih1f = (const float*)d_in[12];
  const float* bhh1f = (const float*)d_in[13];
  const float* Wih1b = (const float*)d_in[14];
  const float* Whh1b = (const float*)d_in[15];
  const float* bih1b = (const float*)d_in[16];
  const float* bhh1b = (const float*)d_in[17];
  const float* Wfc   = (const float*)d_in[18];
  const float* bfc   = (const float*)d_in[19];

  const size_t MR = (size_t)T_*B_;                 // 32768 GEMM rows
  // ws layout (EXACTLY 256 MiB): [xwF 64M | xwB 64M | y 128M]
  float* xwF  = (float*)d_ws;
  float* xwB  = xwF + MR*H_;
  float* bufA = xwF + 2*MR*H_;                     // y0, then y1 in place
  float* probs = (float*)d_out;                    // logits in place, then softmax
  float* hTout = probs + MR*O_;
  // flags live in the probs region of d_out: nothing reads it before the final
  // FC GEMM overwrites it (stream-ordered after both scans). 16 padded
  // counters x 256B = 8KB.
  unsigned int* flags = (unsigned int*)d_out;

  hipMemsetAsync(flags, 0, 8192, stream);

  dim3 blk(256);
  // layer 0 input projections (K=256)
  gemm_bt<<<dim3(MR/128, H_/128), blk, 0, stream>>>(x, Wih0f, bih0f, bhh0f, xwF, (int)MR, H_, I_);
  gemm_bt<<<dim3(MR/128, H_/128), blk, 0, stream>>>(x, Wih0b, bih0b, bhh0b, xwB, (int)MR, H_, I_);
  // layer 0 scan (both directions) -> y0
  rnn_scan<<<64, blk, 0, stream>>>(xwF, xwB, Whh0f, Whh0b, h0, bufA, hTout, flags);
  // layer 1 input projections (K=1024)
  gemm_bt<<<dim3(MR/128, H_/128), blk, 0, stream>>>(bufA, Wih1f, bih1f, bhh1f, xwF, (int)MR, H_, 2*H_);
  gemm_bt<<<dim3(MR/128, H_/128), blk, 0, stream>>>(bufA, Wih1b, bih1b, bhh1b, xwB, (int)MR, H_, 2*H_);
  // layer 1 scan -> y1 (in place over y0)
  rnn_scan<<<64, blk, 0, stream>>>(xwF, xwB, Whh1f, Whh1b, h0 + 2*B_*H_, bufA, hTout + 2*B_*H_, flags + 512);
  // FC head (K=1024, N=128) -> logits into d_out
  gemm_bt<<<dim3(MR/128, 1), blk, 0, stream>>>(bufA, Wfc, bfc, nullptr, probs, (int)MR, O_, 2*H_);
  // softmax in place
  softmax_rows<<<MR/4, blk, 0, stream>>>(probs);
}